// Round 5
// baseline (506.787 us; speedup 1.0000x reference)
//
#include <hip/hip_runtime.h>
#include <hip/hip_bf16.h>

// LSH attention (Reformer-style), B=16, S=4096, D=128, H=8, bucket=64.
// rnorm -> hash (f32 + f64-fallback argmax) -> counting sort ->
// MFMA chunked attention (bf16 3-term split, async-staged, raw barriers) -> divide.

#define B_ 16
#define S_ 4096
#define D_ 128
#define H_ 8
#define C_ 512          // H * n_buckets

typedef __attribute__((ext_vector_type(8))) short bf16x8;
typedef __attribute__((ext_vector_type(4))) short short4v;
typedef __attribute__((ext_vector_type(4))) float f32x4;
typedef __attribute__((ext_vector_type(2))) float f32x2;
typedef __attribute__((ext_vector_type(4))) int int4v;

__device__ __forceinline__ short f2bf(float x) {
    __hip_bfloat16 b = __float2bfloat16(x);   // RNE
    return *reinterpret_cast<short*>(&b);
}
__device__ __forceinline__ float bf2f(short h) {
    unsigned int u = ((unsigned int)(unsigned short)h) << 16;
    float f;
    __builtin_memcpy(&f, &u, 4);
    return f;
}

// barrier that does NOT drain vmcnt (keeps register prefetches in flight);
// lgkmcnt(0) makes this wave's LDS writes/reads complete before crossing.
#define BARRIER() do { asm volatile("s_waitcnt lgkmcnt(0)" ::: "memory"); \
                       __builtin_amdgcn_s_barrier(); \
                       asm volatile("" ::: "memory"); } while (0)

// ---------------------------------------------------------------- row 1/norm
__global__ __launch_bounds__(256) void norm_kernel(const float* __restrict__ qk,
                                                   float* __restrict__ rnrm) {
    int half = threadIdx.x >> 5;
    int lane32 = threadIdx.x & 31;
    size_t row = (size_t)blockIdx.x * 8 + half;
    float4 vv = ((const float4*)(qk + row * D_))[lane32];
    float ss = vv.x * vv.x + vv.y * vv.y + vv.z * vv.z + vv.w * vv.w;
    #pragma unroll
    for (int m = 1; m < 32; m <<= 1) ss += __shfl_xor(ss, m, 64);
    if (lane32 == 0) rnrm[row] = 1.0f / fmaxf(sqrtf(ss), 1e-12f);
}

// ---------------------------------------------------------------- hashing
// f32 packed-FMA main pass; if top-2 margin < 1e-2 (worst-case f32 error is
// ~1e-3), recompute that token's projections in f64 (validated exact path).
__global__ __launch_bounds__(256) void hash_kernel(const float* __restrict__ qk,
                                                   const float* __restrict__ rot,
                                                   int* __restrict__ buckets) {
    __shared__ float qtile[64 * 132];
    __shared__ float rtile[128 * 32];
    int b = blockIdx.x >> 6;
    int tile = blockIdx.x & 63;
    int tid = threadIdx.x;

    const float* qbase = qk + ((size_t)b * S_ + (size_t)tile * 64) * D_;
    #pragma unroll
    for (int u = 0; u < 8; ++u) {
        int fi = u * 256 + tid;
        int row = fi >> 5, c = fi & 31;
        float4 vv = ((const float4*)qbase)[fi];
        *((float4*)(qtile + row * 132 + c * 4)) = vv;
    }

    int tok = tid >> 2, part = tid & 3;
    int t = tile * 64 + tok;

    for (int h = 0; h < H_; ++h) {
        __syncthreads();
        #pragma unroll
        for (int u = 0; u < 4; ++u) {
            int fi = u * 256 + tid;
            int f = fi >> 3, i4 = fi & 7;
            ((float4*)rtile)[f * 8 + i4] = ((const float4*)rot)[f * 64 + h * 8 + i4];
        }
        __syncthreads();

        // ---- f32 pass (packed fma)
        f32x2 pf[4] = {};
        #pragma unroll 4
        for (int f = 0; f < 128; ++f) {
            float q = qtile[tok * 132 + f];
            f32x2 q2 = {q, q};
            float4 r0 = *(const float4*)(rtile + f * 32 + part * 8);
            float4 r1 = *(const float4*)(rtile + f * 32 + part * 8 + 4);
            f32x2 ra = {r0.x, r0.y}, rb = {r0.z, r0.w};
            f32x2 rc = {r1.x, r1.y}, rd = {r1.z, r1.w};
            pf[0] += q2 * ra;
            pf[1] += q2 * rb;
            pf[2] += q2 * rc;
            pf[3] += q2 * rd;
        }
        // local top-2 (value, min-index tiebreak) over (+p, i), (-p, i+32)
        float v1 = -1e30f, v2 = -1e30f; int i1 = 0;
        #pragma unroll
        for (int jj = 0; jj < 8; ++jj) {
            float v = pf[jj >> 1][jj & 1];
            int i = part * 8 + jj;
            if (v > v1 || (v == v1 && i < i1)) { v2 = v1; v1 = v; i1 = i; }
            else v2 = fmaxf(v2, v);
            float nv = -v; int ni = i + 32;
            if (nv > v1 || (nv == v1 && ni < i1)) { v2 = v1; v1 = nv; i1 = ni; }
            else v2 = fmaxf(v2, nv);
        }
        #pragma unroll
        for (int mm = 1; mm <= 2; mm <<= 1) {
            float ov1 = __shfl_xor(v1, mm, 64);
            int   oi1 = __shfl_xor(i1, mm, 64);
            float ov2 = __shfl_xor(v2, mm, 64);
            bool takeOther = (ov1 > v1) || (ov1 == v1 && oi1 < i1);
            float loser = takeOther ? v1 : ov1;
            float nv1 = takeOther ? ov1 : v1;
            int   ni1 = takeOther ? oi1 : i1;
            v2 = fmaxf(fmaxf(v2, ov2), loser);
            v1 = nv1; i1 = ni1;
        }

        int winner = i1;
        if (v1 - v2 < 1e-2f) {          // rare; uniform across the token quad
            double pd[8] = {0, 0, 0, 0, 0, 0, 0, 0};
            #pragma unroll 2
            for (int f = 0; f < 128; ++f) {
                double q = (double)qtile[tok * 132 + f];
                float4 r0 = *((const float4*)(rtile + f * 32 + part * 8));
                float4 r1 = *((const float4*)(rtile + f * 32 + part * 8 + 4));
                pd[0] = fma(q, (double)r0.x, pd[0]);
                pd[1] = fma(q, (double)r0.y, pd[1]);
                pd[2] = fma(q, (double)r0.z, pd[2]);
                pd[3] = fma(q, (double)r0.w, pd[3]);
                pd[4] = fma(q, (double)r1.x, pd[4]);
                pd[5] = fma(q, (double)r1.y, pd[5]);
                pd[6] = fma(q, (double)r1.z, pd[6]);
                pd[7] = fma(q, (double)r1.w, pd[7]);
            }
            double bv = -1e300; int bi = 0;
            #pragma unroll
            for (int ii = 0; ii < 8; ++ii) {
                int i = part * 8 + ii;
                double v = pd[ii];
                if (v > bv || (v == bv && i < bi)) { bv = v; bi = i; }
                double nv = -v; int ni = i + 32;
                if (nv > bv || (nv == bv && ni < bi)) { bv = nv; bi = ni; }
            }
            #pragma unroll
            for (int mm = 1; mm <= 2; mm <<= 1) {
                double ov = __shfl_xor(bv, mm, 64);
                int oi = __shfl_xor(bi, mm, 64);
                if (ov > bv || (ov == bv && oi < bi)) { bv = ov; bi = oi; }
            }
            winner = bi;
        }
        if (part == 0) buckets[(((size_t)b * H_ + h) << 12) + t] = winner;
    }
}

// ---------------------------------------------------------------- stable counting sort
__global__ __launch_bounds__(256) void sort_kernel(const int* __restrict__ buckets,
                                                   int* __restrict__ st) {
    __shared__ unsigned short hist[256][64];
    __shared__ int base[64];
    __shared__ int totals[64];
    int tid = threadIdx.x;
    const int* bkrow = buckets + (size_t)blockIdx.x * S_;

    unsigned int* h32 = (unsigned int*)hist;
    #pragma unroll
    for (int u = 0; u < 32; ++u) h32[u * 256 + tid] = 0;
    __syncthreads();

    #pragma unroll
    for (int u = 0; u < 16; ++u) {
        int t = tid * 16 + u;
        int bk = bkrow[t];
        hist[tid][bk]++;
    }
    __syncthreads();

    if (tid < 64) {
        int bucket = tid;
        int run = 0;
        for (int ch = 0; ch < 256; ++ch) {
            int v = hist[ch][bucket];
            hist[ch][bucket] = (unsigned short)run;
            run += v;
        }
        totals[bucket] = run;
    }
    __syncthreads();
    if (tid == 0) {
        int acc = 0;
        for (int k = 0; k < 64; ++k) { base[k] = acc; acc += totals[k]; }
    }
    __syncthreads();

    int* strow = st + (size_t)blockIdx.x * S_;
    #pragma unroll
    for (int u = 0; u < 16; ++u) {
        int t = tid * 16 + u;
        int bk = bkrow[t];
        int off = hist[tid][bk];
        hist[tid][bk] = (unsigned short)(off + 1);
        strow[base[bk] + off] = t;
    }
}

// ---------------------------------------------------------------- in-reg 4x4 transpose
__device__ __forceinline__ void transpose4(const float4 v, int g, float (&w_)[4]) {
    bool b0 = (g & 1) != 0, b1 = (g & 2) != 0;
    float k0 = b1 ? v.z : v.x;
    float k1 = b1 ? v.w : v.y;
    float s0 = b1 ? v.x : v.z;
    float s1 = b1 ? v.y : v.w;
    float r0 = __shfl_xor(s0, 32, 64);
    float r1 = __shfl_xor(s1, 32, 64);
    float kq_ = b0 ? k1 : k0;
    float rq_ = b0 ? r1 : r0;
    float sk  = b0 ? k0 : k1;
    float sr  = b0 ? r0 : r1;
    float tk_ = __shfl_xor(sk, 16, 64);
    float tr_ = __shfl_xor(sr, 16, 64);
    float A0 = b0 ? tk_ : kq_;
    float A1 = b0 ? kq_ : tk_;
    float B0 = b0 ? tr_ : rq_;
    float B1 = b0 ? rq_ : tr_;
    w_[0] = b1 ? B0 : A0;
    w_[1] = b1 ? B1 : A1;
    w_[2] = b1 ? A0 : B0;
    w_[3] = b1 ? A1 : B1;
}

// ---------------------------------------------------------------- MFMA attention
// One block per (b, chunk c): 64 q vs 128 k (chunks c, c-1 mod 512).
// Self-mask: chunk c is a per-round permutation -> slot equality; chunk c-1
// may be the PREVIOUS hash round (c % 64 == 0) -> token-id comparison mask.
__global__ __launch_bounds__(256, 3) void attn_mfma_kernel(
        const float* __restrict__ qk, const float* __restrict__ rnrm,
        const float* __restrict__ vglob, const int* __restrict__ st,
        float* __restrict__ outnum, float* __restrict__ den) {
    __shared__ int tq_s[64];
    __shared__ int tk1_s[64];
    // union: {khi [0,8192), klo [8192,16384)} | {vhi, vlo} (short indices)
    __shared__ short kvs[16384];

    const int bc = blockIdx.x;
    const int b  = bc >> 9;
    const int c  = bc & 511;
    const int tid = threadIdx.x;
    const int w   = tid >> 6;   // wave 0..3
    const int l   = tid & 63;
    const int g   = l >> 4;     // quad 0..3
    const int m   = l & 15;
    const size_t bS = ((size_t)b << 12);
    const int* stb = st + ((size_t)b << 15);

    if (tid < 64) {
        tq_s[tid]  = stb[c * 64 + tid];
        tk1_s[tid] = stb[((c + 511) & 511) * 64 + tid];
    }
    BARRIER();

    const int qtok_m = tq_s[w * 16 + m];   // this lane's q column token

    float4 kreg[8]; float rn[8];
    float4 va[4], vb[4];
    bf16x8 qh[4], ql[4];
    f32x4 e4[4];
    f32x4 acc_o[8];
    #pragma unroll
    for (int dt = 0; dt < 8; ++dt) acc_o[dt] = (f32x4){0.f, 0.f, 0.f, 0.f};
    float densum = 0.0f;

    auto issue_k = [&](const int* __restrict__ toks) {
        #pragma unroll
        for (int u = 0; u < 8; ++u) {
            int token = u * 8 + (tid >> 5);
            int cc = tid & 31;
            int tkt = toks[token];
            kreg[u] = *(const float4*)(qk + (bS + tkt) * D_ + cc * 4);
            rn[u] = rnrm[bS + tkt];
        }
    };
    auto write_k = [&]() {
        #pragma unroll
        for (int u = 0; u < 8; ++u) {
            int token = u * 8 + (tid >> 5);
            int cc = tid & 31;
            float xv[4] = {kreg[u].x * rn[u], kreg[u].y * rn[u],
                           kreg[u].z * rn[u], kreg[u].w * rn[u]};
            short4v h4, l4;
            #pragma unroll
            for (int j = 0; j < 4; ++j) {
                short hh = f2bf(xv[j]);
                h4[j] = hh;
                l4[j] = f2bf(xv[j] - bf2f(hh));
            }
            int kw = token * 128 + ((((cc >> 1) ^ (token & 7)) << 3) | ((cc & 1) << 2));
            *(short4v*)&kvs[kw] = h4;
            *(short4v*)&kvs[8192 + kw] = l4;
        }
    };
    auto issue_v = [&](const int* __restrict__ toks) {
        #pragma unroll
        for (int up = 0; up < 4; ++up) {
            int kq8 = w * 16 + (up & 1) * 8;
            int cc = (up >> 1) * 16 + m;
            va[up] = *(const float4*)(vglob + (bS + toks[kq8 + g]) * D_ + cc * 4);
            vb[up] = *(const float4*)(vglob + (bS + toks[kq8 + 4 + g]) * D_ + cc * 4);
        }
    };
    auto write_v = [&]() {
        #pragma unroll
        for (int up = 0; up < 4; ++up) {
            int kq8 = w * 16 + (up & 1) * 8;
            int cc = (up >> 1) * 16 + m;
            float wa[4], wb[4];
            transpose4(va[up], g, wa);          // wa[i] = (token kq8+i, dim cc*4+g)
            transpose4(vb[up], g, wb);
            int d = cc * 4 + g;
            int ds = d ^ ((d >> 3) & 7);
            int kg = kq8 >> 3;
            bf16x8 hv, lv;
            #pragma unroll
            for (int i = 0; i < 4; ++i) {
                short hh = f2bf(wa[i]); hv[i] = hh;     lv[i] = f2bf(wa[i] - bf2f(hh));
                short h2 = f2bf(wb[i]); hv[4 + i] = h2; lv[4 + i] = f2bf(wb[i] - bf2f(h2));
            }
            int idx = (kg * 128 + ds) * 8;
            *(bf16x8*)&kvs[idx] = hv;
            *(bf16x8*)&kvs[8192 + idx] = lv;
        }
    };
    // mode 0: self chunk (slot-equality mask); mode 1: look-back chunk
    // (token-id mask via tk1_s — needed when c-1 crosses a hash-round boundary)
    auto qk_pass = [&](int mode) {
        #pragma unroll
        for (int kt = 0; kt < 4; ++kt) {
            f32x4 acc = (f32x4){0.f, 0.f, 0.f, 0.f};
            #pragma unroll
            for (int s4 = 0; s4 < 4; ++s4) {
                int kr = (kt * 16 + m) * 128 + (((s4 * 4 + g) ^ (m & 7)) << 3);
                bf16x8 ah = *(const bf16x8*)&kvs[kr];
                bf16x8 al = *(const bf16x8*)&kvs[8192 + kr];
                acc = __builtin_amdgcn_mfma_f32_16x16x32_bf16(ah, qh[s4], acc, 0, 0, 0);
                acc = __builtin_amdgcn_mfma_f32_16x16x32_bf16(ah, ql[s4], acc, 0, 0, 0);
                acc = __builtin_amdgcn_mfma_f32_16x16x32_bf16(al, qh[s4], acc, 0, 0, 0);
            }
            int4v kt4;
            if (mode == 1) kt4 = *(const int4v*)&tk1_s[kt * 16 + g * 4];
            f32x4 e;
            #pragma unroll
            for (int r = 0; r < 4; ++r) {
                float ev = __expf(acc[r]);
                if (mode == 0) {
                    if (kt == w && (g * 4 + r) == m) ev = 0.0f;
                } else {
                    if (kt4[r] == qtok_m) ev = 0.0f;
                }
                e[r] = ev;
                densum += ev;
            }
            e4[kt] = e;
        }
    };
    auto pv_pass = [&]() {
        #pragma unroll
        for (int s = 0; s < 2; ++s) {
            float pav[8];
            #pragma unroll
            for (int c2 = 0; c2 < 2; ++c2) {
                int srcLane = ((g & 1) * 2 + c2) * 16 + m;
                #pragma unroll
                for (int r = 0; r < 4; ++r) {
                    float v0 = __shfl(e4[2 * s][r], srcLane, 64);
                    float v1 = __shfl(e4[2 * s + 1][r], srcLane, 64);
                    pav[c2 * 4 + r] = (g >> 1) ? v1 : v0;
                }
            }
            bf16x8 pah, pal;
            #pragma unroll
            for (int j = 0; j < 8; ++j) {
                short hh = f2bf(pav[j]);
                pah[j] = hh;
                pal[j] = f2bf(pav[j] - bf2f(hh));
            }
            #pragma unroll
            for (int dt = 0; dt < 8; ++dt) {
                int d = dt * 16 + m;
                int ds = d ^ ((d >> 3) & 7);
                int base = ((s * 4 + g) * 128 + ds) * 8;
                bf16x8 vh = *(const bf16x8*)&kvs[base];
                bf16x8 vl = *(const bf16x8*)&kvs[8192 + base];
                acc_o[dt] = __builtin_amdgcn_mfma_f32_16x16x32_bf16(pah, vh, acc_o[dt], 0, 0, 0);
                acc_o[dt] = __builtin_amdgcn_mfma_f32_16x16x32_bf16(pal, vh, acc_o[dt], 0, 0, 0);
                acc_o[dt] = __builtin_amdgcn_mfma_f32_16x16x32_bf16(pah, vl, acc_o[dt], 0, 0, 0);
            }
        }
    };

    // ---- P1: issue K0 + Q gathers; write K0
    float4 qreg[8];
    issue_k(tq_s);
    {
        const float* qrow = qk + (bS + qtok_m) * D_;
        #pragma unroll
        for (int s4 = 0; s4 < 4; ++s4) {
            qreg[2 * s4]     = *(const float4*)(qrow + s4 * 32 + g * 8);
            qreg[2 * s4 + 1] = *(const float4*)(qrow + s4 * 32 + g * 8 + 4);
        }
    }
    write_k();
    BARRIER();

    // ---- P2: Q frags; issue V0; QK0
    {
        const float scale = 0.08838834764831845f;   // D^-0.5
        #pragma unroll
        for (int s4 = 0; s4 < 4; ++s4) {
            float xv[8] = {qreg[2*s4].x, qreg[2*s4].y, qreg[2*s4].z, qreg[2*s4].w,
                           qreg[2*s4+1].x, qreg[2*s4+1].y, qreg[2*s4+1].z, qreg[2*s4+1].w};
            #pragma unroll
            for (int j = 0; j < 8; ++j) {
                float v = xv[j] * scale;
                short hh = f2bf(v);
                qh[s4][j] = hh;
                ql[s4][j] = f2bf(v - bf2f(hh));
            }
        }
    }
    issue_v(tq_s);
    qk_pass(0);
    BARRIER();

    // ---- P3: issue K1; write V0
    issue_k(tk1_s);
    write_v();
    BARRIER();

    // ---- P4: PV0
    pv_pass();
    BARRIER();

    // ---- P5: write K1
    write_k();
    BARRIER();

    // ---- P6: issue V1; QK1 (token-id mask covers round-boundary look-back)
    issue_v(tk1_s);
    qk_pass(1);
    BARRIER();

    // ---- P7: write V1
    write_v();
    BARRIER();

    // ---- P8: PV1 + epilogue
    pv_pass();

    densum += __shfl_xor(densum, 16, 64);
    densum += __shfl_xor(densum, 32, 64);
    if (g == 0) atomicAdd(den + bS + qtok_m, densum);

    int4v q4tok = *(const int4v*)&tq_s[w * 16 + g * 4];
    #pragma unroll
    for (int r = 0; r < 4; ++r) {
        float* obase = outnum + ((bS + q4tok[r]) * D_);
        #pragma unroll
        for (int dt = 0; dt < 8; ++dt)
            atomicAdd(obase + dt * 16 + m, acc_o[dt][r]);
    }
}

// ---------------------------------------------------------------- divide
__global__ __launch_bounds__(256) void div_kernel(float* __restrict__ out,
                                                  const float* __restrict__ den) {
    int i = blockIdx.x * 256 + threadIdx.x;  // float4 index
    float4 o = ((float4*)out)[i];
    float dn = den[i >> 5];
    ((float4*)out)[i] = make_float4(o.x / dn, o.y / dn, o.z / dn, o.w / dn);
}

// ---------------------------------------------------------------- launch
extern "C" void kernel_launch(void* const* d_in, const int* in_sizes, int n_in,
                              void* d_out, int out_size, void* d_ws, size_t ws_size,
                              hipStream_t stream) {
    const float* qk  = (const float*)d_in[0];
    const float* v   = (const float*)d_in[1];
    const float* rot = (const float*)d_in[2];
    float* out = (float*)d_out;

    char* ws = (char*)d_ws;
    float* rnrm   = (float*)ws;                       //   262,144 B
    int* buckets  = (int*)(ws + 262144);              // 2,097,152 B
    int* st       = (int*)(ws + 2359296);             // 2,097,152 B
    float* den    = (float*)(ws + 4456448);           //   262,144 B

    hipMemsetAsync(out, 0, (size_t)B_ * S_ * D_ * 4, stream);
    hipMemsetAsync(den, 0, (size_t)B_ * S_ * 4, stream);

    norm_kernel<<<B_ * S_ / 8, 256, 0, stream>>>(qk, rnrm);
    hash_kernel<<<B_ * (S_ / 64), 256, 0, stream>>>(qk, rot, buckets);
    sort_kernel<<<B_ * H_, 256, 0, stream>>>(buckets, st);
    attn_mfma_kernel<<<B_ * C_, 256, 0, stream>>>(qk, rnrm, v, st, out, den);
    div_kernel<<<B_ * S_ * D_ / 4 / 256, 256, 0, stream>>>(out, den);
}

// Round 6
// 465.585 us; speedup vs baseline: 1.0885x; 1.0885x over previous
//
#include <hip/hip_runtime.h>
#include <hip/hip_bf16.h>

// LSH attention (Reformer-style), B=16, S=4096, D=128, H=8, bucket=64.
// rnorm -> hash (f32 + f64-fallback argmax) -> counting sort ->
// MFMA chunked attention (raw-qk shared K/Q staging, rn folded into exp,
// XCD-swizzled blocks) -> divide.

#define B_ 16
#define S_ 4096
#define D_ 128
#define H_ 8
#define C_ 512          // H * n_buckets
#define SCALE_ 0.08838834764831845f   // D^-0.5

typedef __attribute__((ext_vector_type(8))) short bf16x8;
typedef __attribute__((ext_vector_type(4))) short short4v;
typedef __attribute__((ext_vector_type(4))) float f32x4;
typedef __attribute__((ext_vector_type(2))) float f32x2;
typedef __attribute__((ext_vector_type(4))) int int4v;

__device__ __forceinline__ short f2bf(float x) {
    __hip_bfloat16 b = __float2bfloat16(x);   // RNE
    return *reinterpret_cast<short*>(&b);
}
__device__ __forceinline__ float bf2f(short h) {
    unsigned int u = ((unsigned int)(unsigned short)h) << 16;
    float f;
    __builtin_memcpy(&f, &u, 4);
    return f;
}

// ---------------------------------------------------------------- row 1/norm
__global__ __launch_bounds__(256) void norm_kernel(const float* __restrict__ qk,
                                                   float* __restrict__ rnrm) {
    int half = threadIdx.x >> 5;
    int lane32 = threadIdx.x & 31;
    size_t row = (size_t)blockIdx.x * 8 + half;
    float4 vv = ((const float4*)(qk + row * D_))[lane32];
    float ss = vv.x * vv.x + vv.y * vv.y + vv.z * vv.z + vv.w * vv.w;
    #pragma unroll
    for (int m = 1; m < 32; m <<= 1) ss += __shfl_xor(ss, m, 64);
    if (lane32 == 0) rnrm[row] = 1.0f / fmaxf(sqrtf(ss), 1e-12f);
}

// ---------------------------------------------------------------- hashing
// f32 packed-FMA main pass; if top-2 margin < 1e-2, recompute in f64.
__global__ __launch_bounds__(256) void hash_kernel(const float* __restrict__ qk,
                                                   const float* __restrict__ rot,
                                                   int* __restrict__ buckets) {
    __shared__ float qtile[64 * 132];
    __shared__ float rtile[128 * 32];
    int b = blockIdx.x >> 6;
    int tile = blockIdx.x & 63;
    int tid = threadIdx.x;

    const float* qbase = qk + ((size_t)b * S_ + (size_t)tile * 64) * D_;
    #pragma unroll
    for (int u = 0; u < 8; ++u) {
        int fi = u * 256 + tid;
        int row = fi >> 5, c = fi & 31;
        float4 vv = ((const float4*)qbase)[fi];
        *((float4*)(qtile + row * 132 + c * 4)) = vv;
    }

    int tok = tid >> 2, part = tid & 3;
    int t = tile * 64 + tok;

    for (int h = 0; h < H_; ++h) {
        __syncthreads();
        #pragma unroll
        for (int u = 0; u < 4; ++u) {
            int fi = u * 256 + tid;
            int f = fi >> 3, i4 = fi & 7;
            ((float4*)rtile)[f * 8 + i4] = ((const float4*)rot)[f * 64 + h * 8 + i4];
        }
        __syncthreads();

        f32x2 pf[4] = {};
        #pragma unroll 4
        for (int f = 0; f < 128; ++f) {
            float q = qtile[tok * 132 + f];
            f32x2 q2 = {q, q};
            float4 r0 = *(const float4*)(rtile + f * 32 + part * 8);
            float4 r1 = *(const float4*)(rtile + f * 32 + part * 8 + 4);
            f32x2 ra = {r0.x, r0.y}, rb = {r0.z, r0.w};
            f32x2 rc = {r1.x, r1.y}, rd = {r1.z, r1.w};
            pf[0] += q2 * ra;
            pf[1] += q2 * rb;
            pf[2] += q2 * rc;
            pf[3] += q2 * rd;
        }
        float v1 = -1e30f, v2 = -1e30f; int i1 = 0;
        #pragma unroll
        for (int jj = 0; jj < 8; ++jj) {
            float v = pf[jj >> 1][jj & 1];
            int i = part * 8 + jj;
            if (v > v1 || (v == v1 && i < i1)) { v2 = v1; v1 = v; i1 = i; }
            else v2 = fmaxf(v2, v);
            float nv = -v; int ni = i + 32;
            if (nv > v1 || (nv == v1 && ni < i1)) { v2 = v1; v1 = nv; i1 = ni; }
            else v2 = fmaxf(v2, nv);
        }
        #pragma unroll
        for (int mm = 1; mm <= 2; mm <<= 1) {
            float ov1 = __shfl_xor(v1, mm, 64);
            int   oi1 = __shfl_xor(i1, mm, 64);
            float ov2 = __shfl_xor(v2, mm, 64);
            bool takeOther = (ov1 > v1) || (ov1 == v1 && oi1 < i1);
            float loser = takeOther ? v1 : ov1;
            float nv1 = takeOther ? ov1 : v1;
            int   ni1 = takeOther ? oi1 : i1;
            v2 = fmaxf(fmaxf(v2, ov2), loser);
            v1 = nv1; i1 = ni1;
        }

        int winner = i1;
        if (v1 - v2 < 1e-2f) {          // rare; uniform across the token quad
            double pd[8] = {0, 0, 0, 0, 0, 0, 0, 0};
            #pragma unroll 2
            for (int f = 0; f < 128; ++f) {
                double q = (double)qtile[tok * 132 + f];
                float4 r0 = *((const float4*)(rtile + f * 32 + part * 8));
                float4 r1 = *((const float4*)(rtile + f * 32 + part * 8 + 4));
                pd[0] = fma(q, (double)r0.x, pd[0]);
                pd[1] = fma(q, (double)r0.y, pd[1]);
                pd[2] = fma(q, (double)r0.z, pd[2]);
                pd[3] = fma(q, (double)r0.w, pd[3]);
                pd[4] = fma(q, (double)r1.x, pd[4]);
                pd[5] = fma(q, (double)r1.y, pd[5]);
                pd[6] = fma(q, (double)r1.z, pd[6]);
                pd[7] = fma(q, (double)r1.w, pd[7]);
            }
            double bv = -1e300; int bi = 0;
            #pragma unroll
            for (int ii = 0; ii < 8; ++ii) {
                int i = part * 8 + ii;
                double v = pd[ii];
                if (v > bv || (v == bv && i < bi)) { bv = v; bi = i; }
                double nv = -v; int ni = i + 32;
                if (nv > bv || (nv == bv && ni < bi)) { bv = nv; bi = ni; }
            }
            #pragma unroll
            for (int mm = 1; mm <= 2; mm <<= 1) {
                double ov = __shfl_xor(bv, mm, 64);
                int oi = __shfl_xor(bi, mm, 64);
                if (ov > bv || (ov == bv && oi < bi)) { bv = ov; bi = oi; }
            }
            winner = bi;
        }
        if (part == 0) buckets[(((size_t)b * H_ + h) << 12) + t] = winner;
    }
}

// ---------------------------------------------------------------- stable counting sort
__global__ __launch_bounds__(256) void sort_kernel(const int* __restrict__ buckets,
                                                   int* __restrict__ st) {
    __shared__ unsigned short hist[256][64];
    __shared__ int base[64];
    __shared__ int totals[64];
    int tid = threadIdx.x;
    const int* bkrow = buckets + (size_t)blockIdx.x * S_;

    unsigned int* h32 = (unsigned int*)hist;
    #pragma unroll
    for (int u = 0; u < 32; ++u) h32[u * 256 + tid] = 0;
    __syncthreads();

    #pragma unroll
    for (int u = 0; u < 16; ++u) {
        int t = tid * 16 + u;
        int bk = bkrow[t];
        hist[tid][bk]++;
    }
    __syncthreads();

    if (tid < 64) {
        int bucket = tid;
        int run = 0;
        for (int ch = 0; ch < 256; ++ch) {
            int v = hist[ch][bucket];
            hist[ch][bucket] = (unsigned short)run;
            run += v;
        }
        totals[bucket] = run;
    }
    __syncthreads();
    if (tid == 0) {
        int acc = 0;
        for (int k = 0; k < 64; ++k) { base[k] = acc; acc += totals[k]; }
    }
    __syncthreads();

    int* strow = st + (size_t)blockIdx.x * S_;
    #pragma unroll
    for (int u = 0; u < 16; ++u) {
        int t = tid * 16 + u;
        int bk = bkrow[t];
        int off = hist[tid][bk];
        hist[tid][bk] = (unsigned short)(off + 1);
        strow[base[bk] + off] = t;
    }
}

// ---------------------------------------------------------------- in-reg 4x4 transpose
__device__ __forceinline__ void transpose4(const float4 v, int g, float (&w_)[4]) {
    bool b0 = (g & 1) != 0, b1 = (g & 2) != 0;
    float k0 = b1 ? v.z : v.x;
    float k1 = b1 ? v.w : v.y;
    float s0 = b1 ? v.x : v.z;
    float s1 = b1 ? v.y : v.w;
    float r0 = __shfl_xor(s0, 32, 64);
    float r1 = __shfl_xor(s1, 32, 64);
    float kq_ = b0 ? k1 : k0;
    float rq_ = b0 ? r1 : r0;
    float sk  = b0 ? k0 : k1;
    float sr  = b0 ? r0 : r1;
    float tk_ = __shfl_xor(sk, 16, 64);
    float tr_ = __shfl_xor(sr, 16, 64);
    float A0 = b0 ? tk_ : kq_;
    float A1 = b0 ? kq_ : tk_;
    float B0 = b0 ? tr_ : rq_;
    float B1 = b0 ? rq_ : tr_;
    w_[0] = b1 ? B0 : A0;
    w_[1] = b1 ? B1 : A1;
    w_[2] = b1 ? A0 : B0;
    w_[3] = b1 ? A1 : B1;
}

// ---------------------------------------------------------------- MFMA attention
// One block per (b, chunk c): 64 q vs 128 k (chunks c, c-1 mod 512).
// Raw qk rows staged in bf16 hi/lo; K-normalization (rnrm*scale) is folded
// into the exp argument per C-row (dots^T rows are k-indexed). Q B-frags are
// read from the same staged LDS buffer (q tokens == self-chunk k tokens).
__global__ __launch_bounds__(256) void attn_mfma_kernel(
        const float* __restrict__ qk, const float* __restrict__ rnrm,
        const float* __restrict__ vglob, const int* __restrict__ st,
        float* __restrict__ outnum, float* __restrict__ den) {
    __shared__ int tq_s[64];
    __shared__ int tk1_s[64];
    __shared__ float rns0[64];
    __shared__ float rns1[64];
    // union: {khi [0,8192), klo [8192,16384)} | {vhi, vlo} (short indices)
    __shared__ short kvs[16384];

    // XCD swizzle: logical L = (p%8)*1024 + p/8 -> each batch (512 blocks)
    // lands on one XCD; its qk/v (4 MB) is L2-resident.
    const int p = blockIdx.x;
    const int bc = (p & 7) * 1024 + (p >> 3);
    const int b  = bc >> 9;
    const int c  = bc & 511;
    const int tid = threadIdx.x;
    const int w   = tid >> 6;   // wave 0..3
    const int l   = tid & 63;
    const int g   = l >> 4;     // quad 0..3
    const int m   = l & 15;
    const size_t bS = ((size_t)b << 12);
    const int* stb = st + ((size_t)b << 15);

    if (tid < 64) {
        int t0 = stb[c * 64 + tid];
        int t1 = stb[((c + 511) & 511) * 64 + tid];
        tq_s[tid]  = t0;
        tk1_s[tid] = t1;
        rns0[tid] = rnrm[bS + t0] * SCALE_;
        rns1[tid] = rnrm[bS + t1] * SCALE_;
    }
    __syncthreads();

    const int qtok_m = tq_s[w * 16 + m];   // this lane's q column token
    const int4v q4tok = *(const int4v*)&tq_s[w * 16 + g * 4];

    bf16x8 qh[4], ql[4];
    f32x4 e4[4];
    f32x4 acc_o[8];
    #pragma unroll
    for (int dt = 0; dt < 8; ++dt) acc_o[dt] = (f32x4){0.f, 0.f, 0.f, 0.f};
    float densum = 0.0f;

    // stage raw qk rows as bf16 hi/lo, swizzled 16B slots (^ row&7)
    auto stage_k = [&](const int* __restrict__ toks) {
        #pragma unroll
        for (int u = 0; u < 8; ++u) {
            int token = u * 8 + (tid >> 5);
            int cc = tid & 31;
            int tkt = toks[token];
            float4 vv = *(const float4*)(qk + (bS + tkt) * D_ + cc * 4);
            float xv[4] = {vv.x, vv.y, vv.z, vv.w};
            short4v h4, l4;
            #pragma unroll
            for (int j = 0; j < 4; ++j) {
                short hh = f2bf(xv[j]);
                h4[j] = hh;
                l4[j] = f2bf(xv[j] - bf2f(hh));
            }
            int kw = token * 128 + ((((cc >> 1) ^ (token & 7)) << 3) | ((cc & 1) << 2));
            *(short4v*)&kvs[kw] = h4;
            *(short4v*)&kvs[8192 + kw] = l4;
        }
    };
    auto stage_v = [&](const int* __restrict__ toks) {
        #pragma unroll
        for (int up = 0; up < 4; ++up) {
            int kq8 = w * 16 + (up & 1) * 8;
            int cc = (up >> 1) * 16 + m;
            float4 va = *(const float4*)(vglob + (bS + toks[kq8 + g]) * D_ + cc * 4);
            float4 vb = *(const float4*)(vglob + (bS + toks[kq8 + 4 + g]) * D_ + cc * 4);
            float wa[4], wb[4];
            transpose4(va, g, wa);              // wa[i] = (token kq8+i, dim cc*4+g)
            transpose4(vb, g, wb);
            int d = cc * 4 + g;
            int ds = d ^ ((d >> 3) & 7);
            int kg = kq8 >> 3;
            bf16x8 hv, lv;
            #pragma unroll
            for (int i = 0; i < 4; ++i) {
                short hh = f2bf(wa[i]); hv[i] = hh;     lv[i] = f2bf(wa[i] - bf2f(hh));
                short h2 = f2bf(wb[i]); hv[4 + i] = h2; lv[4 + i] = f2bf(wb[i] - bf2f(h2));
            }
            int idx = (kg * 128 + ds) * 8;
            *(bf16x8*)&kvs[idx] = hv;
            *(bf16x8*)&kvs[8192 + idx] = lv;
        }
    };
    // mode 0: self chunk (slot-equality mask, rns0); mode 1: look-back chunk
    // (token-id mask via tk1_s — handles hash-round-boundary wrap; rns1)
    auto qk_pass = [&](int mode) {
        const float* rns = (mode == 0) ? rns0 : rns1;
        #pragma unroll
        for (int kt = 0; kt < 4; ++kt) {
            f32x4 acc = (f32x4){0.f, 0.f, 0.f, 0.f};
            #pragma unroll
            for (int s4 = 0; s4 < 4; ++s4) {
                int kr = (kt * 16 + m) * 128 + (((s4 * 4 + g) ^ (m & 7)) << 3);
                bf16x8 ah = *(const bf16x8*)&kvs[kr];
                bf16x8 al = *(const bf16x8*)&kvs[8192 + kr];
                acc = __builtin_amdgcn_mfma_f32_16x16x32_bf16(ah, qh[s4], acc, 0, 0, 0);
                acc = __builtin_amdgcn_mfma_f32_16x16x32_bf16(ah, ql[s4], acc, 0, 0, 0);
                acc = __builtin_amdgcn_mfma_f32_16x16x32_bf16(al, qh[s4], acc, 0, 0, 0);
            }
            f32x4 rn4 = *(const f32x4*)&rns[kt * 16 + g * 4];
            int4v kt4;
            if (mode == 1) kt4 = *(const int4v*)&tk1_s[kt * 16 + g * 4];
            f32x4 e;
            #pragma unroll
            for (int r = 0; r < 4; ++r) {
                float ev = __expf(acc[r] * rn4[r]);
                if (mode == 0) {
                    if (kt == w && (g * 4 + r) == m) ev = 0.0f;
                } else {
                    if (kt4[r] == qtok_m) ev = 0.0f;
                }
                e[r] = ev;
                densum += ev;
            }
            e4[kt] = e;
        }
    };
    auto pv_pass = [&]() {
        #pragma unroll
        for (int s = 0; s < 2; ++s) {
            float pav[8];
            #pragma unroll
            for (int c2 = 0; c2 < 2; ++c2) {
                int srcLane = ((g & 1) * 2 + c2) * 16 + m;
                #pragma unroll
                for (int r = 0; r < 4; ++r) {
                    float v0 = __shfl(e4[2 * s][r], srcLane, 64);
                    float v1 = __shfl(e4[2 * s + 1][r], srcLane, 64);
                    pav[c2 * 4 + r] = (g >> 1) ? v1 : v0;
                }
            }
            bf16x8 pah, pal;
            #pragma unroll
            for (int j = 0; j < 8; ++j) {
                short hh = f2bf(pav[j]);
                pah[j] = hh;
                pal[j] = f2bf(pav[j] - bf2f(hh));
            }
            #pragma unroll
            for (int dt = 0; dt < 8; ++dt) {
                int d = dt * 16 + m;
                int ds = d ^ ((d >> 3) & 7);
                int base = ((s * 4 + g) * 128 + ds) * 8;
                bf16x8 vh = *(const bf16x8*)&kvs[base];
                bf16x8 vl = *(const bf16x8*)&kvs[8192 + base];
                acc_o[dt] = __builtin_amdgcn_mfma_f32_16x16x32_bf16(pah, vh, acc_o[dt], 0, 0, 0);
                acc_o[dt] = __builtin_amdgcn_mfma_f32_16x16x32_bf16(pal, vh, acc_o[dt], 0, 0, 0);
                acc_o[dt] = __builtin_amdgcn_mfma_f32_16x16x32_bf16(pah, vl, acc_o[dt], 0, 0, 0);
            }
        }
    };

    // ---- P1: stage K0 (self chunk = q tokens)
    stage_k(tq_s);
    __syncthreads();

    // ---- P2: Q B-frags directly from staged LDS (q rows == k rows); QK0
    #pragma unroll
    for (int s4 = 0; s4 < 4; ++s4) {
        int qr = (w * 16 + m) * 128 + (((s4 * 4 + g) ^ (m & 7)) << 3);
        qh[s4] = *(const bf16x8*)&kvs[qr];
        ql[s4] = *(const bf16x8*)&kvs[8192 + qr];
    }
    qk_pass(0);
    __syncthreads();

    // ---- P3: stage V0 (overwrites kvs)
    stage_v(tq_s);
    __syncthreads();

    // ---- P4: PV0
    pv_pass();
    __syncthreads();

    // ---- P5: stage K1 (look-back chunk)
    stage_k(tk1_s);
    __syncthreads();

    // ---- P6: QK1
    qk_pass(1);
    __syncthreads();

    // ---- P7: stage V1
    stage_v(tk1_s);
    __syncthreads();

    // ---- P8: PV1 + epilogue
    pv_pass();

    densum += __shfl_xor(densum, 16, 64);
    densum += __shfl_xor(densum, 32, 64);
    if (g == 0) atomicAdd(den + bS + qtok_m, densum);

    #pragma unroll
    for (int r = 0; r < 4; ++r) {
        float* obase = outnum + ((bS + q4tok[r]) * D_);
        #pragma unroll
        for (int dt = 0; dt < 8; ++dt)
            atomicAdd(obase + dt * 16 + m, acc_o[dt][r]);
    }
}

// ---------------------------------------------------------------- divide
__global__ __launch_bounds__(256) void div_kernel(float* __restrict__ out,
                                                  const float* __restrict__ den) {
    int i = blockIdx.x * 256 + threadIdx.x;  // float4 index
    float4 o = ((float4*)out)[i];
    float dn = den[i >> 5];
    ((float4*)out)[i] = make_float4(o.x / dn, o.y / dn, o.z / dn, o.w / dn);
}

// ---------------------------------------------------------------- launch
extern "C" void kernel_launch(void* const* d_in, const int* in_sizes, int n_in,
                              void* d_out, int out_size, void* d_ws, size_t ws_size,
                              hipStream_t stream) {
    const float* qk  = (const float*)d_in[0];
    const float* v   = (const float*)d_in[1];
    const float* rot = (const float*)d_in[2];
    float* out = (float*)d_out;

    char* ws = (char*)d_ws;
    float* rnrm   = (float*)ws;                       //   262,144 B
    int* buckets  = (int*)(ws + 262144);              // 2,097,152 B
    int* st       = (int*)(ws + 2359296);             // 2,097,152 B
    float* den    = (float*)(ws + 4456448);           //   262,144 B

    hipMemsetAsync(out, 0, (size_t)B_ * S_ * D_ * 4, stream);
    hipMemsetAsync(den, 0, (size_t)B_ * S_ * 4, stream);

    norm_kernel<<<B_ * S_ / 8, 256, 0, stream>>>(qk, rnrm);
    hash_kernel<<<B_ * (S_ / 64), 256, 0, stream>>>(qk, rot, buckets);
    sort_kernel<<<B_ * H_, 256, 0, stream>>>(buckets, st);
    attn_mfma_kernel<<<B_ * C_, 256, 0, stream>>>(qk, rnrm, v, st, out, den);
    div_kernel<<<B_ * S_ * D_ / 4 / 256, 256, 0, stream>>>(out, den);
}

// Round 7
// 377.360 us; speedup vs baseline: 1.3430x; 1.2338x over previous
//
#include <hip/hip_runtime.h>
#include <hip/hip_bf16.h>

// LSH attention (Reformer-style), B=16, S=4096, D=128, H=8, bucket=64.
// rnorm -> hash (f32 + f64-fallback argmax) -> counting sort (+inverse perm) ->
// MFMA chunked attention (dense f16 numerator stores, NO atomics) -> combine.

#define B_ 16
#define S_ 4096
#define D_ 128
#define H_ 8
#define C_ 512          // H * n_buckets
#define SCALE_ 0.08838834764831845f   // D^-0.5

typedef __attribute__((ext_vector_type(8))) short bf16x8;
typedef __attribute__((ext_vector_type(4))) short short4v;
typedef __attribute__((ext_vector_type(4))) float f32x4;
typedef __attribute__((ext_vector_type(2))) float f32x2;
typedef __attribute__((ext_vector_type(4))) int int4v;
typedef __attribute__((ext_vector_type(2))) _Float16 f16x2;

__device__ __forceinline__ short f2bf(float x) {
    __hip_bfloat16 b = __float2bfloat16(x);   // RNE
    return *reinterpret_cast<short*>(&b);
}
__device__ __forceinline__ float bf2f(short h) {
    unsigned int u = ((unsigned int)(unsigned short)h) << 16;
    float f;
    __builtin_memcpy(&f, &u, 4);
    return f;
}

// ---------------------------------------------------------------- row 1/norm
__global__ __launch_bounds__(256) void norm_kernel(const float* __restrict__ qk,
                                                   float* __restrict__ rnrm) {
    int half = threadIdx.x >> 5;
    int lane32 = threadIdx.x & 31;
    size_t row = (size_t)blockIdx.x * 8 + half;
    float4 vv = ((const float4*)(qk + row * D_))[lane32];
    float ss = vv.x * vv.x + vv.y * vv.y + vv.z * vv.z + vv.w * vv.w;
    #pragma unroll
    for (int m = 1; m < 32; m <<= 1) ss += __shfl_xor(ss, m, 64);
    if (lane32 == 0) rnrm[row] = 1.0f / fmaxf(sqrtf(ss), 1e-12f);
}

// ---------------------------------------------------------------- hashing
// f32 packed-FMA main pass; if top-2 margin < 1e-2, recompute in f64.
__global__ __launch_bounds__(256) void hash_kernel(const float* __restrict__ qk,
                                                   const float* __restrict__ rot,
                                                   int* __restrict__ buckets) {
    __shared__ float qtile[64 * 132];
    __shared__ float rtile[128 * 32];
    int b = blockIdx.x >> 6;
    int tile = blockIdx.x & 63;
    int tid = threadIdx.x;

    const float* qbase = qk + ((size_t)b * S_ + (size_t)tile * 64) * D_;
    #pragma unroll
    for (int u = 0; u < 8; ++u) {
        int fi = u * 256 + tid;
        int row = fi >> 5, c = fi & 31;
        float4 vv = ((const float4*)qbase)[fi];
        *((float4*)(qtile + row * 132 + c * 4)) = vv;
    }

    int tok = tid >> 2, part = tid & 3;
    int t = tile * 64 + tok;

    for (int h = 0; h < H_; ++h) {
        __syncthreads();
        #pragma unroll
        for (int u = 0; u < 4; ++u) {
            int fi = u * 256 + tid;
            int f = fi >> 3, i4 = fi & 7;
            ((float4*)rtile)[f * 8 + i4] = ((const float4*)rot)[f * 64 + h * 8 + i4];
        }
        __syncthreads();

        f32x2 pf[4] = {};
        #pragma unroll 4
        for (int f = 0; f < 128; ++f) {
            float q = qtile[tok * 132 + f];
            f32x2 q2 = {q, q};
            float4 r0 = *(const float4*)(rtile + f * 32 + part * 8);
            float4 r1 = *(const float4*)(rtile + f * 32 + part * 8 + 4);
            f32x2 ra = {r0.x, r0.y}, rb = {r0.z, r0.w};
            f32x2 rc = {r1.x, r1.y}, rd = {r1.z, r1.w};
            pf[0] += q2 * ra;
            pf[1] += q2 * rb;
            pf[2] += q2 * rc;
            pf[3] += q2 * rd;
        }
        float v1 = -1e30f, v2 = -1e30f; int i1 = 0;
        #pragma unroll
        for (int jj = 0; jj < 8; ++jj) {
            float v = pf[jj >> 1][jj & 1];
            int i = part * 8 + jj;
            if (v > v1 || (v == v1 && i < i1)) { v2 = v1; v1 = v; i1 = i; }
            else v2 = fmaxf(v2, v);
            float nv = -v; int ni = i + 32;
            if (nv > v1 || (nv == v1 && ni < i1)) { v2 = v1; v1 = nv; i1 = ni; }
            else v2 = fmaxf(v2, nv);
        }
        #pragma unroll
        for (int mm = 1; mm <= 2; mm <<= 1) {
            float ov1 = __shfl_xor(v1, mm, 64);
            int   oi1 = __shfl_xor(i1, mm, 64);
            float ov2 = __shfl_xor(v2, mm, 64);
            bool takeOther = (ov1 > v1) || (ov1 == v1 && oi1 < i1);
            float loser = takeOther ? v1 : ov1;
            float nv1 = takeOther ? ov1 : v1;
            int   ni1 = takeOther ? oi1 : i1;
            v2 = fmaxf(fmaxf(v2, ov2), loser);
            v1 = nv1; i1 = ni1;
        }

        int winner = i1;
        if (v1 - v2 < 1e-2f) {          // rare; uniform across the token quad
            double pd[8] = {0, 0, 0, 0, 0, 0, 0, 0};
            #pragma unroll 2
            for (int f = 0; f < 128; ++f) {
                double q = (double)qtile[tok * 132 + f];
                float4 r0 = *((const float4*)(rtile + f * 32 + part * 8));
                float4 r1 = *((const float4*)(rtile + f * 32 + part * 8 + 4));
                pd[0] = fma(q, (double)r0.x, pd[0]);
                pd[1] = fma(q, (double)r0.y, pd[1]);
                pd[2] = fma(q, (double)r0.z, pd[2]);
                pd[3] = fma(q, (double)r0.w, pd[3]);
                pd[4] = fma(q, (double)r1.x, pd[4]);
                pd[5] = fma(q, (double)r1.y, pd[5]);
                pd[6] = fma(q, (double)r1.z, pd[6]);
                pd[7] = fma(q, (double)r1.w, pd[7]);
            }
            double bv = -1e300; int bi = 0;
            #pragma unroll
            for (int ii = 0; ii < 8; ++ii) {
                int i = part * 8 + ii;
                double v = pd[ii];
                if (v > bv || (v == bv && i < bi)) { bv = v; bi = i; }
                double nv = -v; int ni = i + 32;
                if (nv > bv || (nv == bv && ni < bi)) { bv = nv; bi = ni; }
            }
            #pragma unroll
            for (int mm = 1; mm <= 2; mm <<= 1) {
                double ov = __shfl_xor(bv, mm, 64);
                int oi = __shfl_xor(bi, mm, 64);
                if (ov > bv || (ov == bv && oi < bi)) { bv = ov; bi = oi; }
            }
            winner = bi;
        }
        if (part == 0) buckets[(((size_t)b * H_ + h) << 12) + t] = winner;
    }
}

// ---------------------------------------------------------------- stable counting sort
// st[pos] = t, inv[t] = pos (per (b,h))
__global__ __launch_bounds__(256) void sort_kernel(const int* __restrict__ buckets,
                                                   int* __restrict__ st,
                                                   int* __restrict__ inv) {
    __shared__ unsigned short hist[256][64];
    __shared__ int base[64];
    __shared__ int totals[64];
    int tid = threadIdx.x;
    const int* bkrow = buckets + (size_t)blockIdx.x * S_;

    unsigned int* h32 = (unsigned int*)hist;
    #pragma unroll
    for (int u = 0; u < 32; ++u) h32[u * 256 + tid] = 0;
    __syncthreads();

    #pragma unroll
    for (int u = 0; u < 16; ++u) {
        int t = tid * 16 + u;
        int bk = bkrow[t];
        hist[tid][bk]++;
    }
    __syncthreads();

    if (tid < 64) {
        int bucket = tid;
        int run = 0;
        for (int ch = 0; ch < 256; ++ch) {
            int v = hist[ch][bucket];
            hist[ch][bucket] = (unsigned short)run;
            run += v;
        }
        totals[bucket] = run;
    }
    __syncthreads();
    if (tid == 0) {
        int acc = 0;
        for (int k = 0; k < 64; ++k) { base[k] = acc; acc += totals[k]; }
    }
    __syncthreads();

    int* strow = st + (size_t)blockIdx.x * S_;
    int* invrow = inv + (size_t)blockIdx.x * S_;
    #pragma unroll
    for (int u = 0; u < 16; ++u) {
        int t = tid * 16 + u;
        int bk = bkrow[t];
        int off = hist[tid][bk];
        hist[tid][bk] = (unsigned short)(off + 1);
        int pos = base[bk] + off;
        strow[pos] = t;
        invrow[t] = pos;
    }
}

// ---------------------------------------------------------------- in-reg 4x4 transpose
__device__ __forceinline__ void transpose4(const float4 v, int g, float (&w_)[4]) {
    bool b0 = (g & 1) != 0, b1 = (g & 2) != 0;
    float k0 = b1 ? v.z : v.x;
    float k1 = b1 ? v.w : v.y;
    float s0 = b1 ? v.x : v.z;
    float s1 = b1 ? v.y : v.w;
    float r0 = __shfl_xor(s0, 32, 64);
    float r1 = __shfl_xor(s1, 32, 64);
    float kq_ = b0 ? k1 : k0;
    float rq_ = b0 ? r1 : r0;
    float sk  = b0 ? k0 : k1;
    float sr  = b0 ? r0 : r1;
    float tk_ = __shfl_xor(sk, 16, 64);
    float tr_ = __shfl_xor(sr, 16, 64);
    float A0 = b0 ? tk_ : kq_;
    float A1 = b0 ? kq_ : tk_;
    float B0 = b0 ? tr_ : rq_;
    float B1 = b0 ? rq_ : tr_;
    w_[0] = b1 ? B0 : A0;
    w_[1] = b1 ? B1 : A1;
    w_[2] = b1 ? A0 : B0;
    w_[3] = b1 ? A1 : B1;
}

// ---------------------------------------------------------------- MFMA attention
// One block per (b, chunk c): 64 q vs 128 k (chunks c, c-1 mod 512).
// DENSE=true: store f16 numerators + f32 den densely at sorted positions
// (no atomics). DENSE=false: legacy atomic accumulation into outnum/den.
template<bool DENSE>
__global__ __launch_bounds__(256) void attn_mfma_kernel(
        const float* __restrict__ qk, const float* __restrict__ rnrm,
        const float* __restrict__ vglob, const int* __restrict__ st,
        float* __restrict__ outnum, float* __restrict__ den,
        _Float16* __restrict__ snum, float* __restrict__ sden) {
    __shared__ int tq_s[64];
    __shared__ int tk1_s[64];
    __shared__ float rns0[64];
    __shared__ float rns1[64];
    // union: {khi [0,8192), klo [8192,16384)} | {vhi, vlo} (short indices)
    __shared__ short kvs[16384];

    // XCD swizzle: logical L = (p%8)*1024 + p/8 -> each batch (512 blocks)
    // lands on one XCD; its qk/v (4 MB) is L2-resident.
    const int p = blockIdx.x;
    const int bc = (p & 7) * 1024 + (p >> 3);
    const int b  = bc >> 9;
    const int c  = bc & 511;
    const int tid = threadIdx.x;
    const int w   = tid >> 6;   // wave 0..3
    const int l   = tid & 63;
    const int g   = l >> 4;     // quad 0..3
    const int m   = l & 15;
    const size_t bS = ((size_t)b << 12);
    const int* stb = st + ((size_t)b << 15);

    if (tid < 64) {
        int t0 = stb[c * 64 + tid];
        int t1 = stb[((c + 511) & 511) * 64 + tid];
        tq_s[tid]  = t0;
        tk1_s[tid] = t1;
        rns0[tid] = rnrm[bS + t0] * SCALE_;
        rns1[tid] = rnrm[bS + t1] * SCALE_;
    }
    __syncthreads();

    const int qtok_m = tq_s[w * 16 + m];   // this lane's q column token

    bf16x8 qh[4], ql[4];
    f32x4 e4[4];
    f32x4 acc_o[8];
    #pragma unroll
    for (int dt = 0; dt < 8; ++dt) acc_o[dt] = (f32x4){0.f, 0.f, 0.f, 0.f};
    float densum = 0.0f;

    // stage raw qk rows as bf16 hi/lo, swizzled 16B slots (^ row&7)
    auto stage_k = [&](const int* __restrict__ toks) {
        #pragma unroll
        for (int u = 0; u < 8; ++u) {
            int token = u * 8 + (tid >> 5);
            int cc = tid & 31;
            int tkt = toks[token];
            float4 vv = *(const float4*)(qk + (bS + tkt) * D_ + cc * 4);
            float xv[4] = {vv.x, vv.y, vv.z, vv.w};
            short4v h4, l4;
            #pragma unroll
            for (int j = 0; j < 4; ++j) {
                short hh = f2bf(xv[j]);
                h4[j] = hh;
                l4[j] = f2bf(xv[j] - bf2f(hh));
            }
            int kw = token * 128 + ((((cc >> 1) ^ (token & 7)) << 3) | ((cc & 1) << 2));
            *(short4v*)&kvs[kw] = h4;
            *(short4v*)&kvs[8192 + kw] = l4;
        }
    };
    auto stage_v = [&](const int* __restrict__ toks) {
        #pragma unroll
        for (int up = 0; up < 4; ++up) {
            int kq8 = w * 16 + (up & 1) * 8;
            int cc = (up >> 1) * 16 + m;
            float4 va = *(const float4*)(vglob + (bS + toks[kq8 + g]) * D_ + cc * 4);
            float4 vb = *(const float4*)(vglob + (bS + toks[kq8 + 4 + g]) * D_ + cc * 4);
            float wa[4], wb[4];
            transpose4(va, g, wa);              // wa[i] = (token kq8+i, dim cc*4+g)
            transpose4(vb, g, wb);
            int d = cc * 4 + g;
            int ds = d ^ ((d >> 3) & 7);
            int kg = kq8 >> 3;
            bf16x8 hv, lv;
            #pragma unroll
            for (int i = 0; i < 4; ++i) {
                short hh = f2bf(wa[i]); hv[i] = hh;     lv[i] = f2bf(wa[i] - bf2f(hh));
                short h2 = f2bf(wb[i]); hv[4 + i] = h2; lv[4 + i] = f2bf(wb[i] - bf2f(h2));
            }
            int idx = (kg * 128 + ds) * 8;
            *(bf16x8*)&kvs[idx] = hv;
            *(bf16x8*)&kvs[8192 + idx] = lv;
        }
    };
    // mode 0: self chunk (slot-equality mask, rns0); mode 1: look-back chunk
    // (token-id mask via tk1_s — handles hash-round-boundary wrap; rns1)
    auto qk_pass = [&](int mode) {
        const float* rns = (mode == 0) ? rns0 : rns1;
        #pragma unroll
        for (int kt = 0; kt < 4; ++kt) {
            f32x4 acc = (f32x4){0.f, 0.f, 0.f, 0.f};
            #pragma unroll
            for (int s4 = 0; s4 < 4; ++s4) {
                int kr = (kt * 16 + m) * 128 + (((s4 * 4 + g) ^ (m & 7)) << 3);
                bf16x8 ah = *(const bf16x8*)&kvs[kr];
                bf16x8 al = *(const bf16x8*)&kvs[8192 + kr];
                acc = __builtin_amdgcn_mfma_f32_16x16x32_bf16(ah, qh[s4], acc, 0, 0, 0);
                acc = __builtin_amdgcn_mfma_f32_16x16x32_bf16(ah, ql[s4], acc, 0, 0, 0);
                acc = __builtin_amdgcn_mfma_f32_16x16x32_bf16(al, qh[s4], acc, 0, 0, 0);
            }
            f32x4 rn4 = *(const f32x4*)&rns[kt * 16 + g * 4];
            int4v kt4;
            if (mode == 1) kt4 = *(const int4v*)&tk1_s[kt * 16 + g * 4];
            f32x4 e;
            #pragma unroll
            for (int r = 0; r < 4; ++r) {
                float ev = __expf(acc[r] * rn4[r]);
                if (mode == 0) {
                    if (kt == w && (g * 4 + r) == m) ev = 0.0f;
                } else {
                    if (kt4[r] == qtok_m) ev = 0.0f;
                }
                e[r] = ev;
                densum += ev;
            }
            e4[kt] = e;
        }
    };
    auto pv_pass = [&]() {
        #pragma unroll
        for (int s = 0; s < 2; ++s) {
            float pav[8];
            #pragma unroll
            for (int c2 = 0; c2 < 2; ++c2) {
                int srcLane = ((g & 1) * 2 + c2) * 16 + m;
                #pragma unroll
                for (int r = 0; r < 4; ++r) {
                    float v0 = __shfl(e4[2 * s][r], srcLane, 64);
                    float v1 = __shfl(e4[2 * s + 1][r], srcLane, 64);
                    pav[c2 * 4 + r] = (g >> 1) ? v1 : v0;
                }
            }
            bf16x8 pah, pal;
            #pragma unroll
            for (int j = 0; j < 8; ++j) {
                short hh = f2bf(pav[j]);
                pah[j] = hh;
                pal[j] = f2bf(pav[j] - bf2f(hh));
            }
            #pragma unroll
            for (int dt = 0; dt < 8; ++dt) {
                int d = dt * 16 + m;
                int ds = d ^ ((d >> 3) & 7);
                int base = ((s * 4 + g) * 128 + ds) * 8;
                bf16x8 vh = *(const bf16x8*)&kvs[base];
                bf16x8 vl = *(const bf16x8*)&kvs[8192 + base];
                acc_o[dt] = __builtin_amdgcn_mfma_f32_16x16x32_bf16(pah, vh, acc_o[dt], 0, 0, 0);
                acc_o[dt] = __builtin_amdgcn_mfma_f32_16x16x32_bf16(pal, vh, acc_o[dt], 0, 0, 0);
                acc_o[dt] = __builtin_amdgcn_mfma_f32_16x16x32_bf16(pah, vl, acc_o[dt], 0, 0, 0);
            }
        }
    };

    // ---- P1: stage K0 (self chunk = q tokens)
    stage_k(tq_s);
    __syncthreads();

    // ---- P2: Q B-frags directly from staged LDS (q rows == k rows); QK0
    #pragma unroll
    for (int s4 = 0; s4 < 4; ++s4) {
        int qr = (w * 16 + m) * 128 + (((s4 * 4 + g) ^ (m & 7)) << 3);
        qh[s4] = *(const bf16x8*)&kvs[qr];
        ql[s4] = *(const bf16x8*)&kvs[8192 + qr];
    }
    qk_pass(0);
    __syncthreads();

    // ---- P3: stage V0 (overwrites kvs)
    stage_v(tq_s);
    __syncthreads();

    // ---- P4: PV0
    pv_pass();
    __syncthreads();

    // ---- P5: stage K1 (look-back chunk)
    stage_k(tk1_s);
    __syncthreads();

    // ---- P6: QK1
    qk_pass(1);
    __syncthreads();

    // ---- P7: stage V1
    stage_v(tk1_s);
    __syncthreads();

    // ---- P8: PV1 + epilogue
    pv_pass();

    densum += __shfl_xor(densum, 16, 64);
    densum += __shfl_xor(densum, 32, 64);

    if (DENSE) {
        // dense store at sorted positions: row 'row' of chunk c -> pos
        const int h = c >> 6;
        const size_t base = (((size_t)(b * H_ + h)) << 12) + (size_t)(c & 63) * 64;
        #pragma unroll
        for (int r = 0; r < 4; ++r) {
            int row = w * 16 + g * 4 + r;
            _Float16* nrow = snum + (base + row) * D_;
            #pragma unroll
            for (int dt = 0; dt < 8; ++dt)
                nrow[dt * 16 + m] = (_Float16)acc_o[dt][r];
        }
        if (g == 0) sden[base + w * 16 + m] = densum;
    } else {
        if (g == 0) atomicAdd(den + bS + qtok_m, densum);
        int4v q4tok = *(const int4v*)&tq_s[w * 16 + g * 4];
        #pragma unroll
        for (int r = 0; r < 4; ++r) {
            float* obase = outnum + ((bS + q4tok[r]) * D_);
            #pragma unroll
            for (int dt = 0; dt < 8; ++dt)
                atomicAdd(obase + dt * 16 + m, acc_o[dt][r]);
        }
    }
}

// ---------------------------------------------------------------- combine
// out[b,t,:] = sum_h snum[(b,h), inv[t], :] / sum_h sden[(b,h), inv[t]]
__global__ __launch_bounds__(256) void combine_kernel(
        const _Float16* __restrict__ snum, const float* __restrict__ sden,
        const int* __restrict__ inv, float* __restrict__ out) {
    int wv = threadIdx.x >> 6, l = threadIdx.x & 63;
    int t = blockIdx.x * 4 + wv;          // 0 .. B*S-1
    int b = t >> 12, s = t & 4095;
    float s0 = 0.f, s1 = 0.f, dsum = 0.f;
    #pragma unroll
    for (int h = 0; h < H_; ++h) {
        int bh = b * H_ + h;
        int pos = inv[((size_t)bh << 12) + s];
        size_t row = ((size_t)bh << 12) + pos;
        dsum += sden[row];
        f16x2 v = *(const f16x2*)(snum + row * D_ + 2 * l);
        s0 += (float)v[0];
        s1 += (float)v[1];
    }
    float rd = 1.0f / dsum;
    ((float2*)(out + (size_t)t * D_))[l] = make_float2(s0 * rd, s1 * rd);
}

// ---------------------------------------------------------------- divide (fallback)
__global__ __launch_bounds__(256) void div_kernel(float* __restrict__ out,
                                                  const float* __restrict__ den) {
    int i = blockIdx.x * 256 + threadIdx.x;  // float4 index
    float4 o = ((float4*)out)[i];
    float dn = den[i >> 5];
    ((float4*)out)[i] = make_float4(o.x / dn, o.y / dn, o.z / dn, o.w / dn);
}

// ---------------------------------------------------------------- launch
extern "C" void kernel_launch(void* const* d_in, const int* in_sizes, int n_in,
                              void* d_out, int out_size, void* d_ws, size_t ws_size,
                              hipStream_t stream) {
    const float* qk  = (const float*)d_in[0];
    const float* v   = (const float*)d_in[1];
    const float* rot = (const float*)d_in[2];
    float* out = (float*)d_out;

    char* ws = (char*)d_ws;
    float* rnrm    = (float*)ws;                        //   262,144 B
    int* buckets   = (int*)(ws + 262144);               // 2,097,152 B
    int* st        = (int*)(ws + 2359296);              // 2,097,152 B
    int* inv       = (int*)(ws + 4456448);              // 2,097,152 B
    float* sden    = (float*)(ws + 6553600);            // 2,097,152 B
    _Float16* snum = (_Float16*)(ws + 8650752);         // 134,217,728 B
    const size_t need = 8650752ull + 134217728ull;

    norm_kernel<<<B_ * S_ / 8, 256, 0, stream>>>(qk, rnrm);
    hash_kernel<<<B_ * (S_ / 64), 256, 0, stream>>>(qk, rot, buckets);
    sort_kernel<<<B_ * H_, 256, 0, stream>>>(buckets, st, inv);

    if (ws_size >= need) {
        attn_mfma_kernel<true><<<B_ * C_, 256, 0, stream>>>(
            qk, rnrm, v, st, nullptr, nullptr, snum, sden);
        combine_kernel<<<B_ * S_ / 4, 256, 0, stream>>>(snum, sden, inv, out);
    } else {
        float* den = sden;   // reuse slot
        hipMemsetAsync(out, 0, (size_t)B_ * S_ * D_ * 4, stream);
        hipMemsetAsync(den, 0, (size_t)B_ * S_ * 4, stream);
        attn_mfma_kernel<false><<<B_ * C_, 256, 0, stream>>>(
            qk, rnrm, v, st, out, den, nullptr, nullptr);
        div_kernel<<<B_ * S_ * D_ / 4 / 256, 256, 0, stream>>>(out, den);
    }
}